// Round 13
// baseline (144.927 us; speedup 1.0000x reference)
//
#include <hip/hip_runtime.h>
#include <hip/hip_fp16.h>

// MultiViewBEVFusionUnified — two-kernel plan (fp16 intermediate + compacted view lists):
//  A) transpose feats [8][C=64][HW] fp32 -> ws [8][HW][C] fp16 (channel-last)
//  B) per block: 64 voxels; phase1 = projections -> COMPACTED per-voxel valid-view
//     list in LDS (full offsets, half-specific weights) + precomputed 1/cnt;
//     phase2 = wave-per-16-voxels, lane=(channel-pair, pixel-half), exactly-nv
//     iterations of {2 half2 loads, 4 fma}; shfl_xor(32) combine;
//     LDS transpose -> coalesced output stores.
#define BB   2
#define NVV  4
#define CC   64
#define HFF  128
#define WFF  232
#define HW   (HFF*WFF)        // 29696
#define EPSV 1e-5f

// ---------------- Kernel A: channel-last transpose fp32->fp16 ----------------
__global__ __launch_bounds__(256) void transpose_kernel(
    const float* __restrict__ feats, __half* __restrict__ ft)
{
    __shared__ float lds[64][65];
    const int t   = threadIdx.x;
    const int hw0 = blockIdx.x * 64;
    const size_t sbase = (size_t)blockIdx.y * (CC * HW);
    const int l16 = t & 15, g16 = t >> 4;

#pragma unroll
    for (int r = 0; r < 4; ++r) {
        const int c = g16 + 16 * r;
        const float4 v = *(const float4*)(feats + sbase + (size_t)c * HW + hw0 + 4 * l16);
        lds[c][4*l16 + 0] = v.x;
        lds[c][4*l16 + 1] = v.y;
        lds[c][4*l16 + 2] = v.z;
        lds[c][4*l16 + 3] = v.w;
    }
    __syncthreads();
#pragma unroll
    for (int r = 0; r < 4; ++r) {
        const int hw = g16 + 16 * r;
        union { __half2 h[2]; uint2 u; } pk;
        pk.h[0] = __floats2half2_rn(lds[4*l16 + 0][hw], lds[4*l16 + 1][hw]);
        pk.h[1] = __floats2half2_rn(lds[4*l16 + 2][hw], lds[4*l16 + 3][hw]);
        *(uint2*)(ft + sbase + (size_t)(hw0 + hw) * CC + 4 * l16) = pk.u;
    }
}

// ---------------- Kernel B: project + compacted fp16 gather + fuse ----------------
__global__ __launch_bounds__(256) void bev_sample_kernel(
    const __half* __restrict__ ft,      // [8][HW][64] channel-last fp16
    const float* __restrict__ l2c,      // [B,NV,4,4]
    const float* __restrict__ cam2img,  // [B,NV,3,3]
    float* __restrict__ out)            // [B,C,NX,NY,NZ]
{
    __shared__ __align__(16) char smem[17408];
    float2* s_cw  = (float2*)smem;                 // [4][64][2] per-half weights (4KB)
    int2*   s_co  = (int2*)(smem + 4096);          // [4][64] full half-offsets (2KB)
    float*  s_t   = (float*)smem;                  // [64][66] out transpose (aliases, 16896B)
    int*    s_cnt = (int*)(smem + 16896);          // [64] valid counts
    float*  s_scl = (float*)(smem + 17152);        // [64] 1/max(cnt,1)

    const int t   = threadIdx.x;
    const int bid = blockIdx.x;
    const int b   = bid >> 11;
    const int rem = bid & 2047;
    const int xi  = rem >> 4;
    const int yz0 = (rem & 15) << 6;

    if (t < 64) s_cnt[t] = 0;
    __syncthreads();

    // ---- phase 1: projections; thread = (view v = t>>6, voxel j = t&63)
    {
        const int v = t >> 6, j = t & 63;
        const int yzi = yz0 + j;
        const int yi = yzi >> 3, zi = yzi & 7;
        const float X = -25.6f + 0.4f * ((float)xi + 0.5f);
        const float Y = -25.6f + 0.4f * ((float)yi + 0.5f);
        const float Z = -1.0f  + 0.5f * ((float)zi + 0.5f);

        const float* M = l2c + ((b * NVV + v) << 4);
        const float* K = cam2img + (b * NVV + v) * 9;
        const float cx = fmaf(M[0], X, fmaf(M[1], Y, fmaf(M[2],  Z, M[3])));
        const float cy = fmaf(M[4], X, fmaf(M[5], Y, fmaf(M[6],  Z, M[7])));
        const float cz = fmaf(M[8], X, fmaf(M[9], Y, fmaf(M[10], Z, M[11])));
        const float u = fmaf(K[0], cx, fmaf(K[1], cy, K[2] * cz));
        const float w = fmaf(K[3], cx, fmaf(K[4], cy, K[5] * cz));
        const float zc = fmaxf(cz, EPSV);
        const float rz = 1.f / zc;
        const float px = u * rz, py = w * rz;

        const bool valid = (cz > EPSV) && (px >= 0.f) && (px < (float)WFF)
                         && (py >= 0.f) && (py < (float)HFF);

        if (valid) {
            // bilinear (align_corners=False): sample at (px-0.5, py-0.5)
            const float xf = px - 0.5f, yf = py - 0.5f;
            const float x0f = floorf(xf), y0f = floorf(yf);
            const float wx = xf - x0f, wy = yf - y0f;
            const int x0 = (int)x0f, y0 = (int)y0f;   // x0 in [-1,231], y0 in [-1,127]
            const int y1 = y0 + 1;

            // pair base bx: loaded pixels are (bx, bx+1); remap corner weights
            const int bx = min(max(x0, 0), WFF - 2);
            float wLx, wHx;
            if (x0 < 0)            { wLx = wx;       wHx = 0.f; }
            else if (x0 >= WFF-1)  { wLx = 0.f;      wHx = 1.f - wx; }
            else                   { wLx = 1.f - wx; wHx = wx; }

            const float ay0 = (y0 >= 0)     ? (1.f - wy) : 0.f;
            const float ay1 = (y1 <= HFF-1) ? wy         : 0.f;
            const int y0c = max(y0, 0);
            const int y1c = min(y1, HFF - 1);

            const int slot = atomicAdd(&s_cnt[j], 1);
            const int e = slot * 64 + j;
            // half 0 (pixel L): rows (y0,y1) weights; half 1 (pixel H)
            s_cw[e*2 + 0] = make_float2(wLx * ay0, wLx * ay1);
            s_cw[e*2 + 1] = make_float2(wHx * ay0, wHx * ay1);
            // full offsets in halves, including view base (x CC)
            s_co[e] = make_int2((v * HW + y0c * WFF + bx) * CC,
                                (v * HW + y1c * WFF + bx) * CC);
        }
    }
    __syncthreads();
    if (t < 64) s_scl[t] = 1.f / fmaxf((float)s_cnt[t], 1.f);
    __syncthreads();

    // ---- phase 2: gather; wave wv owns voxels wv*16..+15
    // lane l<32: pixel L, channels {2l,2l+1}; lane l>=32: pixel H
    const int wv = t >> 6, lane = t & 63;
    const int half = lane >> 5;
    float2 acc[16];

    const __half* fsl = ft + (size_t)(b * NVV) * (HW * CC);
#pragma unroll
    for (int k = 0; k < 16; ++k) {
        const int j = wv*16 + k;
        const int nv = s_cnt[j];                    // broadcast
        float ax = 0.f, ay = 0.f;
        for (int i = 0; i < nv; ++i) {              // wave-uniform, avg ~1.2 iters
            const int e = i*64 + j;
            const int2   off = s_co[e];             // broadcast
            const float2 w2  = s_cw[e*2 + half];    // 2-addr broadcast
            // 256B pair loads: 64 lanes cover pixels (bx,bx+1) x 64 channels
            const __half2 h0 = *(const __half2*)(fsl + off.x + 2*lane);
            const __half2 h1 = *(const __half2*)(fsl + off.y + 2*lane);
            const float2 f0 = __half22float2(h0);
            const float2 f1 = __half22float2(h1);
            ax = fmaf(f0.x, w2.x, ax); ay = fmaf(f0.y, w2.x, ay);
            ax = fmaf(f1.x, w2.y, ax); ay = fmaf(f1.y, w2.y, ay);
        }
        const float sc = s_scl[j];                  // broadcast
        acc[k] = make_float2(ax * sc, ay * sc);
    }
    __syncthreads();   // phase-2 LDS reads done before aliasing s_t

    // ---- combine corner halves, write transposed to LDS
    const int m2 = (lane & 31) * 2;
#pragma unroll
    for (int k = 0; k < 16; ++k) {
        const float sx = acc[k].x + __shfl_xor(acc[k].x, 32);
        const float sy = acc[k].y + __shfl_xor(acc[k].y, 32);
        if ((k >> 3) == half) {   // half0 writes k=0..7, half1 writes k=8..15
            float2* dst = (float2*)&s_t[(wv*16 + k)*66 + m2];
            *dst = make_float2(sx, sy);
        }
    }
    __syncthreads();

    // ---- coalesced output: lane = voxel, loop channels
    const int jv = t & 63, cr = t >> 6;
    float* ob = out + (size_t)b * (CC * 131072) + (size_t)xi * 1024 + yz0;
#pragma unroll
    for (int r = 0; r < 16; ++r) {
        const int c2 = cr + 4*r;
        ob[(size_t)c2 * 131072 + jv] = s_t[jv*66 + c2];
    }
}

// ---------------- Fallback (round-4 kernel) if ws too small ----------------
#define CG 16
__global__ __launch_bounds__(256) void bev_fuse_kernel(
    const float* __restrict__ feats, const float* __restrict__ l2c,
    const float* __restrict__ cam2img, float* __restrict__ out)
{
    const int tid = blockIdx.x * 256 + threadIdx.x;
    const int b   = tid >> 17;
    const int rem = tid & 131071;
    const int xi  = rem >> 10;
    const int yzi = rem & 1023;
    const int yi  = yzi >> 3;
    const int zi  = yzi & 7;
    const int c0  = blockIdx.y * CG;

    const float X = -25.6f + 0.4f * ((float)xi + 0.5f);
    const float Y = -25.6f + 0.4f * ((float)yi + 0.5f);
    const float Z = -1.0f  + 0.5f * ((float)zi + 0.5f);

    float acc[CG];
#pragma unroll
    for (int c = 0; c < CG; ++c) acc[c] = 0.f;
    float cnt = 0.f;

    for (int v = 0; v < NVV; ++v) {
        const float* M = l2c + ((b * NVV + v) << 4);
        const float* K = cam2img + (b * NVV + v) * 9;
        const float cx = fmaf(M[0], X, fmaf(M[1], Y, fmaf(M[2],  Z, M[3])));
        const float cy = fmaf(M[4], X, fmaf(M[5], Y, fmaf(M[6],  Z, M[7])));
        const float cz = fmaf(M[8], X, fmaf(M[9], Y, fmaf(M[10], Z, M[11])));
        const float u = fmaf(K[0], cx, fmaf(K[1], cy, K[2] * cz));
        const float w = fmaf(K[3], cx, fmaf(K[4], cy, K[5] * cz));
        const float zc = fmaxf(cz, EPSV);
        const float rz = 1.f / zc;
        const float px = u * rz, py = w * rz;
        const bool valid = (cz > EPSV) && (px >= 0.f) && (px < (float)WFF)
                         && (py >= 0.f) && (py < (float)HFF);
        if (!valid) continue;
        cnt += 1.f;
        const float xf = px - 0.5f, yf = py - 0.5f;
        const float x0f = floorf(xf), y0f = floorf(yf);
        const float wx = xf - x0f, wy = yf - y0f;
        const int x0 = (int)x0f, y0 = (int)y0f;
        const int x1 = x0 + 1, y1 = y0 + 1;
        const bool bx0 = (x0 >= 0) & (x0 < WFF);
        const bool bx1 = (x1 >= 0) & (x1 < WFF);
        const bool by0 = (y0 >= 0) & (y0 < HFF);
        const bool by1 = (y1 >= 0) & (y1 < HFF);
        const float w00 = (bx0 && by0) ? (1.f - wx) * (1.f - wy) : 0.f;
        const float w01 = (bx1 && by0) ? wx * (1.f - wy)         : 0.f;
        const float w10 = (bx0 && by1) ? (1.f - wx) * wy         : 0.f;
        const float w11 = (bx1 && by1) ? wx * wy                 : 0.f;
        const int x0c = min(max(x0,0),WFF-1), x1c = min(max(x1,0),WFF-1);
        const int y0c = min(max(y0,0),HFF-1), y1c = min(max(y1,0),HFF-1);
        const int o00 = y0c*WFF+x0c, o01 = y0c*WFF+x1c;
        const int o10 = y1c*WFF+x0c, o11 = y1c*WFF+x1c;
        const float* fb = feats + (size_t)(b*NVV+v)*(CC*HW) + (size_t)c0*HW;
#pragma unroll
        for (int c = 0; c < CG; ++c) {
            const float* fc = fb + c * HW;
            float a = acc[c];
            a = fmaf(fc[o00], w00, a);
            a = fmaf(fc[o01], w01, a);
            a = fmaf(fc[o10], w10, a);
            a = fmaf(fc[o11], w11, a);
            acc[c] = a;
        }
    }
    const float scale = 1.f / fmaxf(cnt, 1.f);
    float* ob = out + (size_t)b*(CC*131072) + (size_t)c0*131072 + xi*1024 + yzi;
#pragma unroll
    for (int c = 0; c < CG; ++c)
        ob[(size_t)c * 131072] = acc[c] * scale;
}

extern "C" void kernel_launch(void* const* d_in, const int* in_sizes, int n_in,
                              void* d_out, int out_size, void* d_ws, size_t ws_size,
                              hipStream_t stream) {
    const float* feats   = (const float*)d_in[0];
    const float* l2c     = (const float*)d_in[1];
    const float* cam2img = (const float*)d_in[2];
    float* out           = (float*)d_out;

    const size_t need = (size_t)BB * NVV * HW * CC * sizeof(__half);  // 30.4 MB
    if (ws_size >= need) {
        __half* ft = (__half*)d_ws;
        dim3 gA(HW / 64, BB * NVV, 1);                 // 464 x 8
        transpose_kernel<<<gA, 256, 0, stream>>>(feats, ft);
        bev_sample_kernel<<<4096, 256, 0, stream>>>(ft, l2c, cam2img, out);
    } else {
        dim3 grid(1024, CC / CG, 1);
        bev_fuse_kernel<<<grid, 256, 0, stream>>>(feats, l2c, cam2img, out);
    }
}